// Round 8
// baseline (402.907 us; speedup 1.0000x reference)
//
#include <hip/hip_runtime.h>
#include <hip/hip_bf16.h>

// MultiHeadAttentionEdges: B=2, N=512, H=128, heads=8, dh=16.
// Main kernel (per (b,i,tz)): 8 j-tiles of one row. E tile reg-staged (NT
// loads) -> swizzled bf16 LDS, Ee = E@We (bf16 MFMA), M = Ee*q*k (k bf16),
// e_out = M@Woe (cached stores), logits via selector-MFMA -> scores (raw).
// lgkm-only barriers (VMEM never drained). XCD swizzle: each XCD owns one
// (b, t-half) -> 64 KB hot K + 64 KB weights per L2.
// Epilogue kernel: softmax in-place on scores, att = P@K, x_out.

#define NB 2
#define NN 512
#define NHID 128
#define BQ 32   // j-tile rows per iteration
#define TZH 8   // iterations per t-half

typedef __bf16 bf16x8 __attribute__((ext_vector_type(8)));
typedef __bf16 bf16x4 __attribute__((ext_vector_type(4)));
typedef float  f32x4  __attribute__((ext_vector_type(4)));
typedef float  vf4    __attribute__((ext_vector_type(4)));   // clang vec for NT builtins

union U16 { uint4 u; bf16x8 v; };

// lgkm-only barrier: publishes LDS writes without draining VMEM.
#define BAR_LGKM() do {                                          \
    asm volatile("s_waitcnt lgkmcnt(0)" ::: "memory");           \
    __builtin_amdgcn_sched_barrier(0);                           \
    __builtin_amdgcn_s_barrier();                                \
    __builtin_amdgcn_sched_barrier(0);                           \
} while (0)

// XCD-aware bijective remap of the 2048-block grid: XCD k (= linear id mod 8)
// gets contiguous Lp range [k*256,(k+1)*256) -> one (b,tz), contiguous i.
__device__ __forceinline__ void swizzle_ibt(int L, int& i, int& b, int& tz) {
    const int Lp = (L & 7) * 256 + (L >> 3);
    b  = Lp >> 10;
    tz = (Lp >> 9) & 1;
    i  = Lp & 511;
}

// ---------------- prep: Qhat/Khat = x@Wq+bq, x@Wk+bk (f32 + bf16 K) ----------
__global__ __launch_bounds__(128)
void proj_kernel(const float* __restrict__ x,
                 const float* __restrict__ Wq, const float* __restrict__ bq,
                 const float* __restrict__ Wk, const float* __restrict__ bk,
                 float* __restrict__ Qhat, float* __restrict__ Khat,
                 __bf16* __restrict__ KbT)
{
    const int row = blockIdx.x;      // b*512+i
    const int c   = threadIdx.x;     // 0..127
    __shared__ float xs[NHID];
    xs[c] = x[(long)row*NHID + c];
    __syncthreads();
    float q = bq[c], k = bk[c];
    #pragma unroll 8
    for (int kk = 0; kk < NHID; ++kk) {
        const float xv = xs[kk];
        q += xv * Wq[kk*NHID + c];
        k += xv * Wk[kk*NHID + c];
    }
    Qhat[(long)row*NHID + c] = q;
    Khat[(long)row*NHID + c] = k;
    KbT [(long)row*NHID + c] = (__bf16)k;
}

// ---------------- prep: transposed bf16 weights WeT[c][k]=We[k][c] ------------
__global__ __launch_bounds__(128)
void wcvt_kernel(const float* __restrict__ We, const float* __restrict__ Woe,
                 __bf16* __restrict__ WeT, __bf16* __restrict__ WoeT)
{
    const int cb = blockIdx.x;   // 0..255
    const int k  = threadIdx.x;  // 0..127
    if (cb < NHID) {
        WeT[cb*NHID + k] = (__bf16)We[k*NHID + cb];
    } else {
        const int c = cb - NHID;
        WoeT[c*NHID + k] = (__bf16)Woe[k*NHID + c];
    }
}

// ---------------- main fused kernel: one block per (b,i,tz) -------------------
__global__ __launch_bounds__(256, 4)
void mha_main(const float* __restrict__ e,
              const float* __restrict__ be,
              const float* __restrict__ boe,
              const float* __restrict__ Qhat,
              const __bf16* __restrict__ KbT,
              const __bf16* __restrict__ WeT,
              const __bf16* __restrict__ WoeT,
              float* __restrict__ eout,
              float* __restrict__ sout)
{
    int i, b, tz;
    swizzle_ibt(blockIdx.y*NN + blockIdx.x, i, b, tz);
    const int tid = threadIdx.x;     // 0..255 (4 waves)
    const int w   = tid >> 6;        // wave 0..3 -> output cols [w*32, w*32+32)
    const int l   = tid & 63;
    const int l15 = l & 15;
    const int lg  = l >> 4;          // 0..3
    const int wcol = w * 32;
    const int t0 = tz * TZH, t1 = t0 + TZH;

    // bf16 tiles, element-XOR swizzle idx ^= (row&7)<<3 (16B granule)
    __shared__ __align__(16) __bf16 Elds[2][BQ*NHID];   // 16 KB
    __shared__ __align__(16) __bf16 Mlds[BQ*NHID];      //  8 KB

    const long rowbi = (long)b*NN + i;
    const float*  Esrc = e    + rowbi*(long)(NN*NHID);
    float*        Edst = eout + rowbi*(long)(NN*NHID);
    const __bf16* Kb   = KbT  + (long)b*NN*NHID;

    // per-lane constants + resident B fragments (We, Woe), col = wcol+ct*16+l15
    float qv[2], bev[2], boev[2];
    bf16x8 fWe[2][4], fWoe[2][4];
    #pragma unroll
    for (int ct = 0; ct < 2; ++ct) {
        const int c = wcol + ct*16 + l15;
        qv[ct]   = Qhat[rowbi*NHID + c] * 0.25f;   // fold 1/sqrt(dh)
        bev[ct]  = be[c];
        boev[ct] = boe[c];
        #pragma unroll
        for (int ks = 0; ks < 4; ++ks) {
            const int kb = ks*32 + lg*8;           // B frag: k=(l>>4)*8+i, col=l15
            U16 ua, ub;
            ua.u = *(const uint4*)(WeT  + c*NHID + kb);
            ub.u = *(const uint4*)(WoeT + c*NHID + kb);
            fWe[ct][ks]  = ua.v;
            fWoe[ct][ks] = ub.v;
        }
    }
    // head-selector predicate for logit MFMA (wave 0): B[n][k] = (k>>4 == n)
    const bool selp[4] = { (0*2 + (lg>>1)) == l15, (1*2 + (lg>>1)) == l15,
                           (2*2 + (lg>>1)) == l15, (3*2 + (lg>>1)) == l15 };

    vf4 rf[4];
    // stage tile t0 (NT read-once loads; cvt to bf16 at write)
    {
        const vf4* src = (const vf4*)(Esrc + (long)t0*(BQ*NHID));
        #pragma unroll
        for (int it = 0; it < 4; ++it)
            rf[it] = __builtin_nontemporal_load(&src[it*256 + tid]);
        #pragma unroll
        for (int it = 0; it < 4; ++it) {
            const int L = (it*256 + tid)*4;
            const int row = L >> 7, k = L & 127;
            bf16x4 v;
            v[0]=(__bf16)rf[it][0]; v[1]=(__bf16)rf[it][1];
            v[2]=(__bf16)rf[it][2]; v[3]=(__bf16)rf[it][3];
            *(bf16x4*)&Elds[0][row*NHID + (k ^ ((row&7)<<3))] = v;
        }
    }
    __syncthreads();

    for (int t = t0; t < t1; ++t) {
        const int cur = t & 1;
        // issue-early prefetch of next E tile (committed after mid-barrier)
        if (t < t1-1) {
            const vf4* src = (const vf4*)(Esrc + (long)(t+1)*(BQ*NHID));
            #pragma unroll
            for (int it = 0; it < 4; ++it)
                rf[it] = __builtin_nontemporal_load(&src[it*256 + tid]);
        }

        // ---- GEMM1: Ee = E@We ; D: col=l15 (=c), row=lg*4+rg
        f32x4 acc1[2][2] = {};
        #pragma unroll
        for (int ks = 0; ks < 4; ++ks) {
            bf16x8 fa[2];
            #pragma unroll
            for (int rt = 0; rt < 2; ++rt) {
                const int row = rt*16 + l15;
                fa[rt] = *(const bf16x8*)&Elds[cur][row*NHID + ((ks*32 + lg*8) ^ ((row&7)<<3))];
            }
            #pragma unroll
            for (int rt = 0; rt < 2; ++rt)
                #pragma unroll
                for (int ct = 0; ct < 2; ++ct)
                    acc1[rt][ct] = __builtin_amdgcn_mfma_f32_16x16x32_bf16(
                        fa[rt], fWe[ct][ks], acc1[rt][ct], 0, 0, 0);
        }

        // ---- elementwise M = (Ee+be)*q*k (k bf16) ; M -> LDS bf16 (swizzled)
        #pragma unroll
        for (int rt = 0; rt < 2; ++rt)
            #pragma unroll
            for (int ct = 0; ct < 2; ++ct) {
                const int c = wcol + ct*16 + l15;
                #pragma unroll
                for (int rg = 0; rg < 4; ++rg) {
                    const int jl = rt*16 + lg*4 + rg;
                    const float ee  = acc1[rt][ct][rg] + bev[ct];
                    const float kvv = (float)Kb[(long)(t*BQ + jl)*NHID + c];
                    const float m   = ee * qv[ct] * kvv;
                    Mlds[jl*NHID + (c ^ ((jl&7)<<3))] = (__bf16)m;
                }
            }

        // mid barrier: publish Mlds (lgkm only; prefetch loads stay in flight)
        BAR_LGKM();

        // write-late: commit prefetched E tile (overlaps GEMM2; published at
        // the END barrier). E[1-cur] was last read in iter t-1 -> WAR-safe.
        if (t < t1-1) {
            #pragma unroll
            for (int it = 0; it < 4; ++it) {
                const int L = (it*256 + tid)*4;
                const int row = L >> 7, k = L & 127;
                bf16x4 v;
                v[0]=(__bf16)rf[it][0]; v[1]=(__bf16)rf[it][1];
                v[2]=(__bf16)rf[it][2]; v[3]=(__bf16)rf[it][3];
                *(bf16x4*)&Elds[1-cur][row*NHID + (k ^ ((row&7)<<3))] = v;
            }
        }

        // ---- GEMM2: e_out tile = M@Woe ; wave0 also: logits = M@Sel
        f32x4 acc2[2][2] = {};
        f32x4 accL[2] = {};
        #pragma unroll
        for (int ks = 0; ks < 4; ++ks) {
            bf16x8 fa[2];
            #pragma unroll
            for (int rt = 0; rt < 2; ++rt) {
                const int row = rt*16 + l15;
                fa[rt] = *(const bf16x8*)&Mlds[row*NHID + ((ks*32 + lg*8) ^ ((row&7)<<3))];
            }
            #pragma unroll
            for (int rt = 0; rt < 2; ++rt)
                #pragma unroll
                for (int ct = 0; ct < 2; ++ct)
                    acc2[rt][ct] = __builtin_amdgcn_mfma_f32_16x16x32_bf16(
                        fa[rt], fWoe[ct][ks], acc2[rt][ct], 0, 0, 0);
            if (w == 0) {
                U16 us;
                const unsigned ones = 0x3f803f80u;   // two bf16 1.0
                us.u.x = selp[ks] ? ones : 0u;
                us.u.y = us.u.x; us.u.z = us.u.x; us.u.w = us.u.x;
                #pragma unroll
                for (int rt = 0; rt < 2; ++rt)
                    accL[rt] = __builtin_amdgcn_mfma_f32_16x16x32_bf16(
                        fa[rt], us.v, accL[rt], 0, 0, 0);
            }
        }
        // stores: e_out tile (cached stores -> L2 coalesces full lines)
        #pragma unroll
        for (int rt = 0; rt < 2; ++rt)
            #pragma unroll
            for (int ct = 0; ct < 2; ++ct) {
                const int c = wcol + ct*16 + l15;
                #pragma unroll
                for (int rg = 0; rg < 4; ++rg) {
                    const int jl = rt*16 + lg*4 + rg;
                    Edst[(long)(t*BQ + jl)*NHID + c] = acc2[rt][ct][rg] + boev[ct];
                }
            }
        // raw logits -> scores buffer (epilogue kernel softmaxes in place)
        if (w == 0 && l15 < 8) {
            float* lrow = sout + ((long)(b*8 + l15)*NN + i)*NN;
            #pragma unroll
            for (int rt = 0; rt < 2; ++rt)
                #pragma unroll
                for (int rg = 0; rg < 4; ++rg)
                    lrow[t*BQ + rt*16 + lg*4 + rg] = accL[rt][rg];
        }

        // end barrier: publish E[next] + retire Mlds reads (lgkm only)
        BAR_LGKM();
    }
}

// ---------------- epilogue: softmax (in-place), att = P@K, x_out --------------
__global__ __launch_bounds__(256)
void epilogue_kernel(const float* __restrict__ mask,
                     const float* __restrict__ Khat,
                     const float* __restrict__ Woh,
                     const float* __restrict__ boh,
                     float* __restrict__ xout,
                     float* __restrict__ sout)
{
    const int L = blockIdx.y*NN + blockIdx.x;
    const int Lp = (L & 7) * 128 + (L >> 3);    // XCD swizzle over 1024 blocks
    const int b = Lp >> 9;
    const int i = Lp & 511;
    const int tid = threadIdx.x;
    const int w   = tid >> 6;
    const int l   = tid & 63;

    __shared__ float Llog[8][NN];
    __shared__ float AttP[2][NHID];
    __shared__ float AttF[NHID];

    const long rowbi = (long)b*NN + i;
    const float* mrow = mask + rowbi*NN;
    const float* Kb   = Khat + (long)b*NN*NHID;

    #pragma unroll
    for (int hh = 0; hh < 2; ++hh) {
        const int h = w*2 + hh;
        float* srow = sout + ((long)(b*8 + h)*NN + i)*NN;
        float vb[8];
        float mx = -1e30f;
        #pragma unroll
        for (int q = 0; q < 8; ++q) {
            const int j = q*64 + l;
            const float v = srow[j] + mrow[j];
            vb[q] = v; mx = fmaxf(mx, v);
        }
        #pragma unroll
        for (int mm = 1; mm < 64; mm <<= 1) mx = fmaxf(mx, __shfl_xor(mx, mm));
        float sum = 0.f;
        #pragma unroll
        for (int q = 0; q < 8; ++q) { vb[q] = __expf(vb[q] - mx); sum += vb[q]; }
        #pragma unroll
        for (int mm = 1; mm < 64; mm <<= 1) sum += __shfl_xor(sum, mm);
        const float inv = 1.f / sum;
        #pragma unroll
        for (int q = 0; q < 8; ++q) {
            const int j = q*64 + l;
            const float p = vb[q]*inv;
            Llog[h][j] = p;
            srow[j] = p;
        }
    }
    __syncthreads();

    // att[c] = sum_j P[c>>4][j] * Khat[b][j][c]   (V = K)
    {
        const int half = tid >> 7;
        const int c = tid & 127;
        const int h = c >> 4;
        float a0 = 0.f, a1 = 0.f, a2 = 0.f, a3 = 0.f;
        const float* kp = Kb + (long)(half*256)*NHID + c;
        const float* pp = &Llog[h][half*256];
        #pragma unroll 4
        for (int j = 0; j < 256; j += 4) {
            a0 += pp[j]   * kp[(long)(j  )*NHID];
            a1 += pp[j+1] * kp[(long)(j+1)*NHID];
            a2 += pp[j+2] * kp[(long)(j+2)*NHID];
            a3 += pp[j+3] * kp[(long)(j+3)*NHID];
        }
        AttP[half][c] = (a0 + a1) + (a2 + a3);
    }
    __syncthreads();
    if (tid < NHID) AttF[tid] = AttP[0][tid] + AttP[1][tid];
    __syncthreads();

    if (tid < NHID) {
        const int c = tid;
        float a0 = boh[c], a1 = 0.f;
        #pragma unroll 8
        for (int k = 0; k < NHID; k += 2) {
            a0 += AttF[k]   * Woh[(k  )*NHID + c];
            a1 += AttF[k+1] * Woh[(k+1)*NHID + c];
        }
        xout[rowbi*NHID + c] = a0 + a1;
    }
}

extern "C" void kernel_launch(void* const* d_in, const int* in_sizes, int n_in,
                              void* d_out, int out_size, void* d_ws, size_t ws_size,
                              hipStream_t stream) {
    const float* x    = (const float*)d_in[0];
    const float* e    = (const float*)d_in[1];
    const float* mask = (const float*)d_in[2];
    const float* Wq   = (const float*)d_in[3];
    const float* bq   = (const float*)d_in[4];
    const float* Wk   = (const float*)d_in[5];
    const float* bk   = (const float*)d_in[6];
    const float* We   = (const float*)d_in[7];
    const float* be   = (const float*)d_in[8];
    const float* Woh  = (const float*)d_in[9];
    const float* boh  = (const float*)d_in[10];
    const float* Woe  = (const float*)d_in[11];
    const float* boe  = (const float*)d_in[12];

    float*  Qhat = (float*)d_ws;                 // 512 KB
    float*  Khat = Qhat + NB*NN*NHID;            // 512 KB
    __bf16* WeT  = (__bf16*)(Khat + NB*NN*NHID); // 32 KB
    __bf16* WoeT = WeT + NHID*NHID;              // 32 KB
    __bf16* KbT  = WoeT + NHID*NHID;             // 256 KB

    float* xout = (float*)d_out;                     // [2,512,128]
    float* eout = xout + (long)NB*NN*NHID;           // [2,512,512,128]
    float* sout = eout + (long)NB*NN*NN*NHID;        // [2,8,512,512]

    proj_kernel<<<dim3(NB*NN), 128, 0, stream>>>(x, Wq, bq, Wk, bk,
                                                 Qhat, Khat, KbT);
    wcvt_kernel<<<dim3(2*NHID), 128, 0, stream>>>(We, Woe, WeT, WoeT);
    mha_main<<<dim3(NN, 2*NB), 256, 0, stream>>>(e, be, boe, Qhat, KbT,
                                                 WeT, WoeT, eout, sout);
    epilogue_kernel<<<dim3(NN, NB), 256, 0, stream>>>(mask, Khat, Woh, boh,
                                                      xout, sout);
}

// Round 9
// 349.783 us; speedup vs baseline: 1.1519x; 1.1519x over previous
//
#include <hip/hip_runtime.h>
#include <hip/hip_bf16.h>

// MultiHeadAttentionEdges: B=2, N=512, H=128, heads=8, dh=16.
// Main kernel: block = (b, j-tile of 32, i-chunk of 16); iterates i.
// K-tile in REGISTERS (loaded once/block), E tile NT-read contiguous 16KB ->
// swizzled bf16 LDS (double-buffered), Ee=E@We, M=Ee*q*k, e_out=M@Woe
// (contiguous 16KB store), logits via selector-MFMA -> scores raw.
// lgkm-only barriers. Epilogue: softmax in-place, att=P@K, x_out.

#define NB 2
#define NN 512
#define NHID 128
#define BJ 32    // j rows per block
#define BI 16    // i's per block

typedef __bf16 bf16x8 __attribute__((ext_vector_type(8)));
typedef __bf16 bf16x4 __attribute__((ext_vector_type(4)));
typedef float  f32x4  __attribute__((ext_vector_type(4)));
typedef float  vf4    __attribute__((ext_vector_type(4)));

union U16 { uint4 u; bf16x8 v; };

#define BAR_LGKM() do {                                          \
    asm volatile("s_waitcnt lgkmcnt(0)" ::: "memory");           \
    __builtin_amdgcn_sched_barrier(0);                           \
    __builtin_amdgcn_s_barrier();                                \
    __builtin_amdgcn_sched_barrier(0);                           \
} while (0)

// ---------------- prep: Qhat/Khat = x@Wq+bq, x@Wk+bk (f32 + bf16 K) ----------
__global__ __launch_bounds__(128)
void proj_kernel(const float* __restrict__ x,
                 const float* __restrict__ Wq, const float* __restrict__ bq,
                 const float* __restrict__ Wk, const float* __restrict__ bk,
                 float* __restrict__ Qhat, float* __restrict__ Khat,
                 __bf16* __restrict__ KbT)
{
    const int row = blockIdx.x;      // b*512+i
    const int c   = threadIdx.x;     // 0..127
    __shared__ float xs[NHID];
    xs[c] = x[(long)row*NHID + c];
    __syncthreads();
    float q = bq[c], k = bk[c];
    #pragma unroll 8
    for (int kk = 0; kk < NHID; ++kk) {
        const float xv = xs[kk];
        q += xv * Wq[kk*NHID + c];
        k += xv * Wk[kk*NHID + c];
    }
    Qhat[(long)row*NHID + c] = q;
    Khat[(long)row*NHID + c] = k;
    KbT [(long)row*NHID + c] = (__bf16)k;
}

// ---------------- prep: transposed bf16 weights WeT[c][k]=We[k][c] ------------
__global__ __launch_bounds__(128)
void wcvt_kernel(const float* __restrict__ We, const float* __restrict__ Woe,
                 __bf16* __restrict__ WeT, __bf16* __restrict__ WoeT)
{
    const int cb = blockIdx.x;   // 0..255
    const int k  = threadIdx.x;  // 0..127
    if (cb < NHID) {
        WeT[cb*NHID + k] = (__bf16)We[k*NHID + cb];
    } else {
        const int c = cb - NHID;
        WoeT[c*NHID + k] = (__bf16)Woe[k*NHID + c];
    }
}

// ---------------- main fused kernel: block = (b, jt, ic) ----------------------
__global__ __launch_bounds__(256, 4)
void mha_main(const float* __restrict__ e,
              const float* __restrict__ be,
              const float* __restrict__ boe,
              const float* __restrict__ Qhat,
              const __bf16* __restrict__ KbT,
              const __bf16* __restrict__ WeT,
              const __bf16* __restrict__ WoeT,
              float* __restrict__ eout,
              float* __restrict__ sout)
{
    // XCD swizzle: XCD k gets contiguous Lp range -> shares (b,jt) K-tile+weights
    const int L  = blockIdx.x;                 // 0..1023
    const int Lp = (L & 7) * 128 + (L >> 3);
    const int b  = Lp >> 9;                    // 0..1
    const int jt = (Lp >> 5) & 15;             // 0..15
    const int ic = Lp & 31;                    // 0..31
    const int j0 = jt * BJ;
    const int i0 = ic * BI;

    const int tid = threadIdx.x;     // 0..255 (4 waves)
    const int w   = tid >> 6;        // wave -> output cols [w*32, w*32+32)
    const int l   = tid & 63;
    const int l15 = l & 15;
    const int lg  = l >> 4;          // 0..3
    const int wcol = w * 32;

    __shared__ __align__(16) __bf16 Elds[2][BJ*NHID];   // 16 KB (swizzled)
    __shared__ __align__(16) __bf16 Mlds[BJ*NHID];      //  8 KB (swizzled)

    // resident B fragments (We, Woe) + biases, col = wcol+ct*16+l15
    float bev[2], boev[2];
    bf16x8 fWe[2][4], fWoe[2][4];
    #pragma unroll
    for (int ct = 0; ct < 2; ++ct) {
        const int c = wcol + ct*16 + l15;
        bev[ct]  = be[c];
        boev[ct] = boe[c];
        #pragma unroll
        for (int ks = 0; ks < 4; ++ks) {
            const int kb = ks*32 + lg*8;
            U16 ua, ub;
            ua.u = *(const uint4*)(WeT  + c*NHID + kb);
            ub.u = *(const uint4*)(WoeT + c*NHID + kb);
            fWe[ct][ks]  = ua.v;
            fWoe[ct][ks] = ub.v;
        }
    }
    // K-tile in registers: once per block. kreg[rt][ct][rg] = K[j0+jl][c]
    float kreg[2][2][4];
    #pragma unroll
    for (int rt = 0; rt < 2; ++rt)
        #pragma unroll
        for (int ct = 0; ct < 2; ++ct)
            #pragma unroll
            for (int rg = 0; rg < 4; ++rg)
                kreg[rt][ct][rg] = (float)KbT[
                    (long)(b*NN + j0 + rt*16 + lg*4 + rg)*NHID + wcol + ct*16 + l15];
    // head-selector predicate for logit MFMA (wave 0)
    const bool selp[4] = { (0*2 + (lg>>1)) == l15, (1*2 + (lg>>1)) == l15,
                           (2*2 + (lg>>1)) == l15, (3*2 + (lg>>1)) == l15 };

    // per-i tile base: e[b][i][j0..j0+31][:] contiguous 16KB
    const float* Qb = Qhat + ((long)b*NN + i0)*NHID;

    vf4 rf[4];
#define EADDR(II) (e + (((long)(b*NN + i0 + (II))*NN + j0) << 7))
    {   // stage tile for i0
        const vf4* src = (const vf4*)EADDR(0);
        #pragma unroll
        for (int it = 0; it < 4; ++it)
            rf[it] = __builtin_nontemporal_load(&src[it*256 + tid]);
        #pragma unroll
        for (int it = 0; it < 4; ++it) {
            const int Lx = (it*256 + tid)*4;
            const int row = Lx >> 7, k = Lx & 127;
            bf16x4 v;
            v[0]=(__bf16)rf[it][0]; v[1]=(__bf16)rf[it][1];
            v[2]=(__bf16)rf[it][2]; v[3]=(__bf16)rf[it][3];
            *(bf16x4*)&Elds[0][row*NHID + (k ^ ((row&7)<<3))] = v;
        }
    }
    __syncthreads();

    for (int ii = 0; ii < BI; ++ii) {
        const int i   = i0 + ii;
        const int cur = ii & 1;
        // issue-early prefetch of next E tile
        if (ii < BI-1) {
            const vf4* src = (const vf4*)EADDR(ii+1);
            #pragma unroll
            for (int it = 0; it < 4; ++it)
                rf[it] = __builtin_nontemporal_load(&src[it*256 + tid]);
        }
        // q values for this i (consumed after GEMM1; issued early)
        float qv[2];
        #pragma unroll
        for (int ct = 0; ct < 2; ++ct)
            qv[ct] = Qb[(long)ii*NHID + wcol + ct*16 + l15] * 0.25f;

        // ---- GEMM1: Ee = E@We ; D: col=l15 (=c), row=lg*4+rg
        f32x4 acc1[2][2] = {};
        #pragma unroll
        for (int ks = 0; ks < 4; ++ks) {
            bf16x8 fa[2];
            #pragma unroll
            for (int rt = 0; rt < 2; ++rt) {
                const int row = rt*16 + l15;
                fa[rt] = *(const bf16x8*)&Elds[cur][row*NHID + ((ks*32 + lg*8) ^ ((row&7)<<3))];
            }
            #pragma unroll
            for (int rt = 0; rt < 2; ++rt)
                #pragma unroll
                for (int ct = 0; ct < 2; ++ct)
                    acc1[rt][ct] = __builtin_amdgcn_mfma_f32_16x16x32_bf16(
                        fa[rt], fWe[ct][ks], acc1[rt][ct], 0, 0, 0);
        }

        // ---- elementwise M = (Ee+be)*q*k ; M -> LDS bf16 (swizzled)
        #pragma unroll
        for (int rt = 0; rt < 2; ++rt)
            #pragma unroll
            for (int ct = 0; ct < 2; ++ct) {
                const int c = wcol + ct*16 + l15;
                #pragma unroll
                for (int rg = 0; rg < 4; ++rg) {
                    const int jl = rt*16 + lg*4 + rg;
                    const float m = (acc1[rt][ct][rg] + bev[ct]) * qv[ct] * kreg[rt][ct][rg];
                    Mlds[jl*NHID + (c ^ ((jl&7)<<3))] = (__bf16)m;
                }
            }

        BAR_LGKM();   // publish Mlds (VMEM stays in flight)

        // write-late: commit prefetched E tile into other buffer
        if (ii < BI-1) {
            #pragma unroll
            for (int it = 0; it < 4; ++it) {
                const int Lx = (it*256 + tid)*4;
                const int row = Lx >> 7, k = Lx & 127;
                bf16x4 v;
                v[0]=(__bf16)rf[it][0]; v[1]=(__bf16)rf[it][1];
                v[2]=(__bf16)rf[it][2]; v[3]=(__bf16)rf[it][3];
                *(bf16x4*)&Elds[1-cur][row*NHID + (k ^ ((row&7)<<3))] = v;
            }
        }

        // ---- GEMM2: e_out tile = M@Woe ; wave0 also: logits = M@Sel
        f32x4 acc2[2][2] = {};
        f32x4 accL[2] = {};
        #pragma unroll
        for (int ks = 0; ks < 4; ++ks) {
            bf16x8 fa[2];
            #pragma unroll
            for (int rt = 0; rt < 2; ++rt) {
                const int row = rt*16 + l15;
                fa[rt] = *(const bf16x8*)&Mlds[row*NHID + ((ks*32 + lg*8) ^ ((row&7)<<3))];
            }
            #pragma unroll
            for (int rt = 0; rt < 2; ++rt)
                #pragma unroll
                for (int ct = 0; ct < 2; ++ct)
                    acc2[rt][ct] = __builtin_amdgcn_mfma_f32_16x16x32_bf16(
                        fa[rt], fWoe[ct][ks], acc2[rt][ct], 0, 0, 0);
            if (w == 0) {
                U16 us;
                const unsigned ones = 0x3f803f80u;
                us.u.x = selp[ks] ? ones : 0u;
                us.u.y = us.u.x; us.u.z = us.u.x; us.u.w = us.u.x;
                #pragma unroll
                for (int rt = 0; rt < 2; ++rt)
                    accL[rt] = __builtin_amdgcn_mfma_f32_16x16x32_bf16(
                        fa[rt], us.v, accL[rt], 0, 0, 0);
            }
        }
        // stores: e_out tile (contiguous 16KB region, single writer)
        float* Edst = eout + (((long)(b*NN + i)*NN + j0) << 7);
        #pragma unroll
        for (int rt = 0; rt < 2; ++rt)
            #pragma unroll
            for (int ct = 0; ct < 2; ++ct) {
                const int c = wcol + ct*16 + l15;
                #pragma unroll
                for (int rg = 0; rg < 4; ++rg) {
                    const int jl = rt*16 + lg*4 + rg;
                    Edst[jl*NHID + c] = acc2[rt][ct][rg] + boev[ct];
                }
            }
        // raw logits -> scores (epilogue softmaxes in place)
        if (w == 0 && l15 < 8) {
            float* lrow = sout + (((long)(b*8 + l15)*NN + i)*NN + j0);
            #pragma unroll
            for (int rt = 0; rt < 2; ++rt)
                #pragma unroll
                for (int rg = 0; rg < 4; ++rg)
                    lrow[rt*16 + lg*4 + rg] = accL[rt][rg];
        }

        BAR_LGKM();   // publish E[next] + retire Mlds reads
    }
#undef EADDR
}

// ---------------- epilogue: softmax (in-place), att = P@K, x_out --------------
__global__ __launch_bounds__(256)
void epilogue_kernel(const float* __restrict__ mask,
                     const float* __restrict__ Khat,
                     const float* __restrict__ Woh,
                     const float* __restrict__ boh,
                     float* __restrict__ xout,
                     float* __restrict__ sout)
{
    const int L = blockIdx.y*NN + blockIdx.x;
    const int Lp = (L & 7) * 128 + (L >> 3);    // XCD swizzle over 1024 blocks
    const int b = Lp >> 9;
    const int i = Lp & 511;
    const int tid = threadIdx.x;
    const int w   = tid >> 6;
    const int l   = tid & 63;

    __shared__ float Llog[8][NN];
    __shared__ float AttP[2][NHID];
    __shared__ float AttF[NHID];

    const long rowbi = (long)b*NN + i;
    const float* mrow = mask + rowbi*NN;
    const float* Kb   = Khat + (long)b*NN*NHID;

    #pragma unroll
    for (int hh = 0; hh < 2; ++hh) {
        const int h = w*2 + hh;
        float* srow = sout + ((long)(b*8 + h)*NN + i)*NN;
        float vb[8];
        float mx = -1e30f;
        #pragma unroll
        for (int q = 0; q < 8; ++q) {
            const int j = q*64 + l;
            const float v = srow[j] + mrow[j];
            vb[q] = v; mx = fmaxf(mx, v);
        }
        #pragma unroll
        for (int mm = 1; mm < 64; mm <<= 1) mx = fmaxf(mx, __shfl_xor(mx, mm));
        float sum = 0.f;
        #pragma unroll
        for (int q = 0; q < 8; ++q) { vb[q] = __expf(vb[q] - mx); sum += vb[q]; }
        #pragma unroll
        for (int mm = 1; mm < 64; mm <<= 1) sum += __shfl_xor(sum, mm);
        const float inv = 1.f / sum;
        #pragma unroll
        for (int q = 0; q < 8; ++q) {
            const int j = q*64 + l;
            const float p = vb[q]*inv;
            Llog[h][j] = p;
            srow[j] = p;
        }
    }
    __syncthreads();

    // att[c] = sum_j P[c>>4][j] * Khat[b][j][c]   (V = K)
    {
        const int half = tid >> 7;
        const int c = tid & 127;
        const int h = c >> 4;
        float a0 = 0.f, a1 = 0.f, a2 = 0.f, a3 = 0.f;
        const float* kp = Kb + (long)(half*256)*NHID + c;
        const float* pp = &Llog[h][half*256];
        #pragma unroll 4
        for (int j = 0; j < 256; j += 4) {
            a0 += pp[j]   * kp[(long)(j  )*NHID];
            a1 += pp[j+1] * kp[(long)(j+1)*NHID];
            a2 += pp[j+2] * kp[(long)(j+2)*NHID];
            a3 += pp[j+3] * kp[(long)(j+3)*NHID];
        }
        AttP[half][c] = (a0 + a1) + (a2 + a3);
    }
    __syncthreads();
    if (tid < NHID) AttF[tid] = AttP[0][tid] + AttP[1][tid];
    __syncthreads();

    if (tid < NHID) {
        const int c = tid;
        float a0 = boh[c], a1 = 0.f;
        #pragma unroll 8
        for (int k = 0; k < NHID; k += 2) {
            a0 += AttF[k]   * Woh[(k  )*NHID + c];
            a1 += AttF[k+1] * Woh[(k+1)*NHID + c];
        }
        xout[rowbi*NHID + c] = a0 + a1;
    }
}

extern "C" void kernel_launch(void* const* d_in, const int* in_sizes, int n_in,
                              void* d_out, int out_size, void* d_ws, size_t ws_size,
                              hipStream_t stream) {
    const float* x    = (const float*)d_in[0];
    const float* e    = (const float*)d_in[1];
    const float* mask = (const float*)d_in[2];
    const float* Wq   = (const float*)d_in[3];
    const float* bq   = (const float*)d_in[4];
    const float* Wk   = (const float*)d_in[5];
    const float* bk   = (const float*)d_in[6];
    const float* We   = (const float*)d_in[7];
    const float* be   = (const float*)d_in[8];
    const float* Woh  = (const float*)d_in[9];
    const float* boh  = (const float*)d_in[10];
    const float* Woe  = (const float*)d_in[11];
    const float* boe  = (const float*)d_in[12];

    float*  Qhat = (float*)d_ws;                 // 512 KB
    float*  Khat = Qhat + NB*NN*NHID;            // 512 KB
    __bf16* WeT  = (__bf16*)(Khat + NB*NN*NHID); // 32 KB
    __bf16* WoeT = WeT + NHID*NHID;              // 32 KB
    __bf16* KbT  = WoeT + NHID*NHID;             // 256 KB

    float* xout = (float*)d_out;                     // [2,512,128]
    float* eout = xout + (long)NB*NN*NHID;           // [2,512,512,128]
    float* sout = eout + (long)NB*NN*NN*NHID;        // [2,8,512,512]

    proj_kernel<<<dim3(NB*NN), 128, 0, stream>>>(x, Wq, bq, Wk, bk,
                                                 Qhat, Khat, KbT);
    wcvt_kernel<<<dim3(2*NHID), 128, 0, stream>>>(We, Woe, WeT, WoeT);
    mha_main<<<dim3(1024), 256, 0, stream>>>(e, be, boe, Qhat, KbT,
                                             WeT, WoeT, eout, sout);
    epilogue_kernel<<<dim3(NN, NB), 256, 0, stream>>>(mask, Khat, Woh, boh,
                                                      xout, sout);
}